// Round 3
// baseline (106.579 us; speedup 1.0000x reference)
//
#include <hip/hip_runtime.h>
#include <hip/hip_bf16.h>

#define NPTS  8192
#define NFEAT 256
#define CHUNK 256
#define NCHUNK (NPTS / CHUNK)   // 32 ref-chunks -> 32x32 = 1024 blocks for argmin

// ws layout: [0, 64KB) keys u64[8192]; [64KB, 64KB+128KB) float4 refs {x,y,z,|t1|^2}
#define WS_KEYS_OFF 0
#define WS_REF_OFF  65536

__global__ __launch_bounds__(256) void prep_kernel(const float* __restrict__ t1f,
                                                   float4* __restrict__ ref,
                                                   unsigned long long* __restrict__ keys) {
    int i = blockIdx.x * 256 + threadIdx.x;
    float x = t1f[i], y = t1f[NPTS + i], z = t1f[2 * NPTS + i];
    // numpy: np.sum(t1*t1, axis=1) over length-3 axis = sequential RNE (x^2+y^2)+z^2
    float n1 = __fadd_rn(__fadd_rn(__fmul_rn(x, x), __fmul_rn(y, y)), __fmul_rn(z, z));
    ref[i]  = make_float4(x, y, z, n1);
    keys[i] = ~0ULL;   // re-init every call (ws is re-poisoned to 0xAA)
}

__global__ __launch_bounds__(256) void argmin_kernel(const float* __restrict__ t2f,
                                                     const float4* __restrict__ ref,
                                                     unsigned long long* __restrict__ keys) {
    int j    = blockIdx.x * 256 + threadIdx.x;   // query index, coalesced
    int base = blockIdx.y * CHUNK;               // reference chunk (wave-uniform)

    float qx = t2f[j], qy = t2f[NPTS + j], qz = t2f[2 * NPTS + j];
    float n2 = __fadd_rn(__fadd_rn(__fmul_rn(qx, qx), __fmul_rn(qy, qy)), __fmul_rn(qz, qz));

    // Replicate np f32 expanded form exactly:
    //   dot = ((x1*x2) + y1*y2) + z1*z2   (einsum SOP loop, sequential, no fma)
    //   d2  = (n1 + n2) - 2*dot           (expression order; 2*dot exact)
    // __f*_rn intrinsics prevent fma contraction.
    float inf = __int_as_float(0x7f800000);
    float b0 = inf, b1 = inf;                 // two chains for ILP
    int   i0 = base, i1 = base + 1;

    #pragma unroll 4
    for (int k = 0; k < CHUNK; k += 2) {
        float4 p = ref[base + k];             // wave-uniform address -> broadcast
        float4 q = ref[base + k + 1];
        float dot0 = __fadd_rn(__fadd_rn(__fmul_rn(p.x, qx), __fmul_rn(p.y, qy)), __fmul_rn(p.z, qz));
        float d20  = __fsub_rn(__fadd_rn(p.w, n2), __fmul_rn(2.0f, dot0));
        float dot1 = __fadd_rn(__fadd_rn(__fmul_rn(q.x, qx), __fmul_rn(q.y, qy)), __fmul_rn(q.z, qz));
        float d21  = __fsub_rn(__fadd_rn(q.w, n2), __fmul_rn(2.0f, dot1));
        if (d20 < b0) { b0 = d20; i0 = base + k; }       // strict < -> first occurrence
        if (d21 < b1) { b1 = d21; i1 = base + k + 1; }
    }

    float best = b0; int idx = i0;
    if (b1 < b0 || (b1 == b0 && i1 < i0)) { best = b1; idx = i1; }

    // signed-float -> order-isomorphic u32 (d2 can be negative via cancellation),
    // then pack index in low 13 bits: atomicMin = min d2, tie -> min idx (np first-occurrence)
    unsigned ub = __float_as_uint(best);
    ub ^= ((unsigned)((int)ub >> 31)) | 0x80000000u;
    unsigned long long key = ((unsigned long long)ub << 13) | (unsigned)idx;
    atomicMin(keys + j, key);
}

__global__ __launch_bounds__(256) void gather_kernel(const float* __restrict__ emb1,
                                                     const float* __restrict__ emb2,
                                                     const unsigned long long* __restrict__ keys,
                                                     float* __restrict__ out) {
    int j0 = (blockIdx.x * 256 + threadIdx.x) * 4;  // 4 consecutive columns per thread
    int f  = blockIdx.y;                            // feature row, uniform per block
    float4 v;
    if (f < NFEAT) {
        const float* row = emb1 + (size_t)f * NPTS;
        v.x = row[(int)(keys[j0 + 0] & 8191ULL)];   // scattered 4B reads, L1/L2-resident row
        v.y = row[(int)(keys[j0 + 1] & 8191ULL)];
        v.z = row[(int)(keys[j0 + 2] & 8191ULL)];
        v.w = row[(int)(keys[j0 + 3] & 8191ULL)];
    } else {
        v = *(const float4*)(emb2 + (size_t)(f - NFEAT) * NPTS + j0);  // coalesced 16B
    }
    *(float4*)(out + (size_t)f * NPTS + j0) = v;    // coalesced 16B store
}

extern "C" void kernel_launch(void* const* d_in, const int* in_sizes, int n_in,
                              void* d_out, int out_size, void* d_ws, size_t ws_size,
                              hipStream_t stream) {
    const float* emb1 = (const float*)d_in[0];
    const float* emb2 = (const float*)d_in[1];
    const float* t1   = (const float*)d_in[2];
    const float* t2   = (const float*)d_in[3];
    float* out = (float*)d_out;

    unsigned long long* keys = (unsigned long long*)((char*)d_ws + WS_KEYS_OFF);
    float4*             ref  = (float4*)((char*)d_ws + WS_REF_OFF);

    prep_kernel<<<dim3(NPTS / 256), 256, 0, stream>>>(t1, ref, keys);
    argmin_kernel<<<dim3(NPTS / 256, NCHUNK), 256, 0, stream>>>(t2, ref, keys);
    gather_kernel<<<dim3(NPTS / 1024, 2 * NFEAT), 256, 0, stream>>>(emb1, emb2, keys, out);
}

// Round 6
// 106.538 us; speedup vs baseline: 1.0004x; 1.0004x over previous
//
#include <hip/hip_runtime.h>

#define NPTS   8192
#define NFEAT  256
#define RCHUNK 256              // refs per chunk
#define NCHUNK (NPTS / RCHUNK)  // 32
#define QG     512              // queries per block (2 per thread)
#define NQG    (NPTS / QG)      // 16

// ws layout: [0, 2MB) partial keys u64[NCHUNK][NPTS]; [2MB, 2MB+32KB) idx u32[NPTS]
#define WS_PART_OFF 0
#define WS_IDX_OFF  (NCHUNK * NPTS * 8)

__device__ __forceinline__ unsigned long long pack_key(float d2, int idx) {
    // signed-float -> order-isomorphic u32 (d2 can be negative via cancellation),
    // index in low 13 bits: u64 min == (min d2, tie -> min idx) = np first-occurrence
    unsigned ub = __float_as_uint(d2);
    ub ^= ((unsigned)((int)ub >> 31)) | 0x80000000u;
    return ((unsigned long long)ub << 13) | (unsigned)idx;
}

__global__ __launch_bounds__(256) void argmin_kernel(const float* __restrict__ t1,
                                                     const float* __restrict__ t2,
                                                     unsigned long long* __restrict__ part) {
#pragma clang fp contract(off)   // forbid FMA contraction: must match np f32 RNE exactly
    __shared__ float4 sref[RCHUNK];
    const int tid = threadIdx.x;
    const int qg  = blockIdx.x;   // query group 0..15
    const int rc  = blockIdx.y;   // ref chunk   0..31

    // Stage this chunk's refs into LDS, computing n1 = (x^2+y^2)+z^2 (np sum order).
    {
        int r = rc * RCHUNK + tid;
        float x = t1[r], y = t1[NPTS + r], z = t1[2 * NPTS + r];
        float n1 = (x * x + y * y) + z * z;
        sref[tid] = make_float4(x, y, z, n1);
    }
    __syncthreads();

    // Two queries per thread: one LDS broadcast feeds 2 distance computations.
    const int j0 = qg * QG + tid;
    const int j1 = j0 + 256;
    float qx0 = t2[j0], qy0 = t2[NPTS + j0], qz0 = t2[2 * NPTS + j0];
    float qx1 = t2[j1], qy1 = t2[NPTS + j1], qz1 = t2[2 * NPTS + j1];
    float n20 = (qx0 * qx0 + qy0 * qy0) + qz0 * qz0;
    float n21 = (qx1 * qx1 + qy1 * qy1) + qz1 * qz1;

    const float inf = __int_as_float(0x7f800000);
    float b0 = inf, b1 = inf;
    int   i0 = 0,   i1 = 0;

    #pragma unroll 4
    for (int k = 0; k < RCHUNK; ++k) {
        float4 p = sref[k];  // wave-uniform address -> LDS broadcast, conflict-free
        // np expanded form, exact op order: dot = (x1x2 + y1y2) + z1z2 ; d2 = (n1+n2) - 2*dot
        float dot0 = (p.x * qx0 + p.y * qy0) + p.z * qz0;
        float d20  = (p.w + n20) - 2.0f * dot0;
        float dot1 = (p.x * qx1 + p.y * qy1) + p.z * qz1;
        float d21  = (p.w + n21) - 2.0f * dot1;
        if (d20 < b0) { b0 = d20; i0 = k; }   // strict < keeps first occurrence
        if (d21 < b1) { b1 = d21; i1 = k; }
    }

    part[rc * NPTS + j0] = pack_key(b0, rc * RCHUNK + i0);  // coalesced 8B stores
    part[rc * NPTS + j1] = pack_key(b1, rc * RCHUNK + i1);
}

__global__ __launch_bounds__(256) void reduce_kernel(const unsigned long long* __restrict__ part,
                                                     unsigned* __restrict__ idx_out) {
    int j = blockIdx.x * 256 + threadIdx.x;
    unsigned long long m = part[j];
    #pragma unroll
    for (int s = 1; s < NCHUNK; ++s) {          // 32 coalesced L2-resident loads
        unsigned long long k = part[s * NPTS + j];
        m = k < m ? k : m;                      // u64 min: d2 then lowest idx
    }
    idx_out[j] = (unsigned)(m & 8191ULL);
}

__global__ __launch_bounds__(256) void gather_kernel(const float* __restrict__ emb1,
                                                     const float* __restrict__ emb2,
                                                     const unsigned* __restrict__ idx,
                                                     float* __restrict__ out) {
    int j0 = (blockIdx.x * 256 + threadIdx.x) * 4;  // 4 consecutive columns per thread
    int f  = blockIdx.y;                            // feature row, uniform per block
    float4 v;
    if (f < NFEAT) {
        const float* row = emb1 + (size_t)f * NPTS; // 32KB row: L1-resident after warm
        uint4 id = *(const uint4*)(idx + j0);
        v.x = row[id.x];
        v.y = row[id.y];
        v.z = row[id.z];
        v.w = row[id.w];
    } else {
        v = *(const float4*)(emb2 + (size_t)(f - NFEAT) * NPTS + j0);  // coalesced 16B
    }
    *(float4*)(out + (size_t)f * NPTS + j0) = v;    // coalesced 16B store
}

extern "C" void kernel_launch(void* const* d_in, const int* in_sizes, int n_in,
                              void* d_out, int out_size, void* d_ws, size_t ws_size,
                              hipStream_t stream) {
    const float* emb1 = (const float*)d_in[0];
    const float* emb2 = (const float*)d_in[1];
    const float* t1   = (const float*)d_in[2];
    const float* t2   = (const float*)d_in[3];
    float* out = (float*)d_out;

    unsigned long long* part = (unsigned long long*)((char*)d_ws + WS_PART_OFF);
    unsigned*           idx  = (unsigned*)((char*)d_ws + WS_IDX_OFF);

    argmin_kernel<<<dim3(NQG, NCHUNK), 256, 0, stream>>>(t1, t2, part);
    reduce_kernel<<<dim3(NPTS / 256), 256, 0, stream>>>(part, idx);
    gather_kernel<<<dim3(NPTS / 1024, 2 * NFEAT), 256, 0, stream>>>(emb1, emb2, idx, out);
}

// Round 7
// 105.144 us; speedup vs baseline: 1.0136x; 1.0133x over previous
//
#include <hip/hip_runtime.h>

#define NPTS   8192
#define NFEAT  256
#define RCHUNK 128              // refs per chunk
#define NCHUNK (NPTS / RCHUNK)  // 64 chunks
#define QG     512              // queries per block (2 per thread)
#define NQG    (NPTS / QG)      // 16  -> argmin grid 16 x 64 = 1024 blocks (4 waves/SIMD)
#define GCOLS  32               // columns per gather block

// ws layout: [0, 4MB) partial keys u64[NCHUNK][NPTS]
#define WS_PART_OFF 0

__device__ __forceinline__ unsigned long long pack_key(float d2, int idx) {
    // signed-float -> order-isomorphic u32 (d2 can be negative via cancellation),
    // index in low 13 bits: u64 min == (min d2, tie -> min idx) = np first-occurrence
    unsigned ub = __float_as_uint(d2);
    ub ^= ((unsigned)((int)ub >> 31)) | 0x80000000u;
    return ((unsigned long long)ub << 13) | (unsigned)idx;
}

__global__ __launch_bounds__(256) void argmin_kernel(const float* __restrict__ t1,
                                                     const float* __restrict__ t2,
                                                     unsigned long long* __restrict__ part) {
#pragma clang fp contract(off)   // forbid FMA contraction: must match np f32 RNE exactly
    __shared__ float4 sref[RCHUNK];
    const int tid = threadIdx.x;
    const int qg  = blockIdx.x;   // query group 0..15
    const int rc  = blockIdx.y;   // ref chunk   0..63

    // Stage this chunk's refs into LDS with n1 = (x^2+y^2)+z^2 (np sum order).
    if (tid < RCHUNK) {
        int r = rc * RCHUNK + tid;
        float x = t1[r], y = t1[NPTS + r], z = t1[2 * NPTS + r];
        sref[tid] = make_float4(x, y, z, (x * x + y * y) + z * z);
    }
    __syncthreads();

    // Two queries per thread: one LDS broadcast feeds 2 distance computations.
    const int j0 = qg * QG + tid;
    const int j1 = j0 + 256;
    float qx0 = t2[j0], qy0 = t2[NPTS + j0], qz0 = t2[2 * NPTS + j0];
    float qx1 = t2[j1], qy1 = t2[NPTS + j1], qz1 = t2[2 * NPTS + j1];
    float n20 = (qx0 * qx0 + qy0 * qy0) + qz0 * qz0;
    float n21 = (qx1 * qx1 + qy1 * qy1) + qz1 * qz1;

    const float inf = __int_as_float(0x7f800000);
    float b0 = inf, b1 = inf;
    int   i0 = 0,   i1 = 0;

    #pragma unroll 4
    for (int k = 0; k < RCHUNK; ++k) {
        float4 p = sref[k];  // wave-uniform address -> LDS broadcast, conflict-free
        // np expanded form, exact op order: dot = (x1x2 + y1y2) + z1z2 ; d2 = (n1+n2) - 2*dot
        float dot0 = (p.x * qx0 + p.y * qy0) + p.z * qz0;
        float d20  = (p.w + n20) - 2.0f * dot0;
        float dot1 = (p.x * qx1 + p.y * qy1) + p.z * qz1;
        float d21  = (p.w + n21) - 2.0f * dot1;
        if (d20 < b0) { b0 = d20; i0 = k; }   // strict < keeps first occurrence
        if (d21 < b1) { b1 = d21; i1 = k; }
    }

    part[(size_t)rc * NPTS + j0] = pack_key(b0, rc * RCHUNK + i0);  // coalesced 8B stores
    part[(size_t)rc * NPTS + j1] = pack_key(b1, rc * RCHUNK + i1);
}

// Fused reduce + gather: each block owns GCOLS consecutive output columns.
__global__ __launch_bounds__(256) void gather_kernel(const float* __restrict__ emb1,
                                                     const float* __restrict__ emb2,
                                                     const unsigned long long* __restrict__ part,
                                                     float* __restrict__ out) {
    __shared__ unsigned long long skey[GCOLS][9];   // padded: breaks bank aliasing
    __shared__ int sidx[GCOLS];
    const int tid   = threadIdx.x;
    const int jbase = blockIdx.x * GCOLS;

    // Phase 1: per-column u64-key min over the 64 chunk partials (deterministic).
    {
        int c = tid & 31, g = tid >> 5;            // 8 threads per column
        size_t j = (size_t)(jbase + c);
        unsigned long long m = ~0ULL;
        #pragma unroll
        for (int s8 = 0; s8 < 8; ++s8) {
            unsigned long long k = part[(size_t)(g * 8 + s8) * NPTS + j];  // L2-resident
            m = k < m ? k : m;
        }
        skey[c][g] = m;
    }
    __syncthreads();
    if (tid < GCOLS) {
        unsigned long long m = skey[tid][0];
        #pragma unroll
        for (int g = 1; g < 8; ++g) {
            unsigned long long k = skey[tid][g];
            m = k < m ? k : m;
        }
        sidx[tid] = (int)(m & 8191ULL);            // min d2, tie -> lowest index
    }
    __syncthreads();

    // Phase 2: 512 feature rows x 32 cols; float4 over columns.
    // f is wave-uniform per pass (t>>3 spans 0..7 within a wave) -> uniform branch.
    #pragma unroll
    for (int p = 0; p < 16; ++p) {
        int f  = p * 32 + (tid >> 3);
        int c0 = (tid & 7) * 4;
        float4 v;
        if (f < NFEAT) {
            const float* row = emb1 + (size_t)f * NPTS;   // 32KB row, L1/L2-resident
            v.x = row[sidx[c0 + 0]];
            v.y = row[sidx[c0 + 1]];
            v.z = row[sidx[c0 + 2]];
            v.w = row[sidx[c0 + 3]];
        } else {
            v = *(const float4*)(emb2 + (size_t)(f - NFEAT) * NPTS + jbase + c0);
        }
        *(float4*)(out + (size_t)f * NPTS + jbase + c0) = v;   // coalesced 16B stores
    }
}

extern "C" void kernel_launch(void* const* d_in, const int* in_sizes, int n_in,
                              void* d_out, int out_size, void* d_ws, size_t ws_size,
                              hipStream_t stream) {
    const float* emb1 = (const float*)d_in[0];
    const float* emb2 = (const float*)d_in[1];
    const float* t1   = (const float*)d_in[2];
    const float* t2   = (const float*)d_in[3];
    float* out = (float*)d_out;

    unsigned long long* part = (unsigned long long*)((char*)d_ws + WS_PART_OFF);

    argmin_kernel<<<dim3(NQG, NCHUNK), 256, 0, stream>>>(t1, t2, part);
    gather_kernel<<<dim3(NPTS / GCOLS), 256, 0, stream>>>(emb1, emb2, part, out);
}

// Round 8
// 104.611 us; speedup vs baseline: 1.0188x; 1.0051x over previous
//
#include <hip/hip_runtime.h>

#define NPTS   8192
#define NFEAT  256
#define RCHUNK 128              // refs per chunk
#define NCHUNK (NPTS / RCHUNK)  // 64 chunks
#define QG     512              // queries per block (2 per thread, packed)
#define NQG    (NPTS / QG)      // 16  -> argmin grid 16 x 64 = 1024 blocks (4 waves/SIMD)
#define GCOLS  32               // columns per gather block

// ws layout: [0, 4MB) partial keys u64[NCHUNK][NPTS]
#define WS_PART_OFF 0

typedef float f32x2 __attribute__((ext_vector_type(2)));

// Packed fp32 ops (VOP3P): per-half IEEE RNE mul/add, cannot be FMA-contracted.
__device__ __forceinline__ f32x2 pk_mul(f32x2 a, f32x2 b) {
    f32x2 d; asm("v_pk_mul_f32 %0, %1, %2" : "=v"(d) : "v"(a), "v"(b)); return d;
}
__device__ __forceinline__ f32x2 pk_add(f32x2 a, f32x2 b) {
    f32x2 d; asm("v_pk_add_f32 %0, %1, %2" : "=v"(d) : "v"(a), "v"(b)); return d;
}

__device__ __forceinline__ unsigned long long pack_key(float d2, int idx) {
    // signed-float -> order-isomorphic u32 (d2 can be negative via cancellation),
    // index in low 13 bits: u64 min == (min d2, tie -> min idx) = np first-occurrence
    unsigned ub = __float_as_uint(d2);
    ub ^= ((unsigned)((int)ub >> 31)) | 0x80000000u;
    return ((unsigned long long)ub << 13) | (unsigned)idx;
}

struct RefDup { f32x2 x, y, z, w; };   // each component duplicated into both halves

__global__ __launch_bounds__(256) void argmin_kernel(const float* __restrict__ t1,
                                                     const float* __restrict__ t2,
                                                     unsigned long long* __restrict__ part) {
#pragma clang fp contract(off)   // scalar prologue must also stay RNE, no FMA
    __shared__ RefDup sref[RCHUNK];
    const int tid = threadIdx.x;
    const int qg  = blockIdx.x;   // query group 0..15
    const int rc  = blockIdx.y;   // ref chunk   0..63

    // Stage refs into LDS pre-duplicated: {x,x},{y,y},{z,z},{n1,n1}.
    // n1 = (x^2+y^2)+z^2 in np's sequential sum order.
    if (tid < RCHUNK) {
        int r = rc * RCHUNK + tid;
        float x = t1[r], y = t1[NPTS + r], z = t1[2 * NPTS + r];
        float n1 = (x * x + y * y) + z * z;
        RefDup s; s.x = (f32x2){x, x}; s.y = (f32x2){y, y};
        s.z = (f32x2){z, z}; s.w = (f32x2){n1, n1};
        sref[tid] = s;
    }
    __syncthreads();

    // Two queries per thread, packed into lo/hi halves.
    const int j0 = qg * QG + tid;
    const int j1 = j0 + 256;
    float qx0 = t2[j0], qy0 = t2[NPTS + j0], qz0 = t2[2 * NPTS + j0];
    float qx1 = t2[j1], qy1 = t2[NPTS + j1], qz1 = t2[2 * NPTS + j1];
    float n20 = (qx0 * qx0 + qy0 * qy0) + qz0 * qz0;
    float n21 = (qx1 * qx1 + qy1 * qy1) + qz1 * qz1;

    const f32x2 qx = {qx0, qx1}, qy = {qy0, qy1}, qz = {qz0, qz1};
    const f32x2 n2 = {n20, n21};
    const f32x2 cm2 = {-2.0f, -2.0f};

    const float inf = __int_as_float(0x7f800000);
    float b0 = inf, b1 = inf;
    int   i0 = 0,   i1 = 0;

    #pragma unroll 4
    for (int k = 0; k < RCHUNK; ++k) {
        RefDup p = sref[k];   // wave-uniform addr -> 2x ds_read_b128 broadcast, conflict-free
        // np expanded form, exact op order per half:
        //   dot = (x1*x2 + y1*y2) + z1*z2
        //   d2  = (n1 + n2) + (dot * -2)     == (n1+n2) - 2*dot bit-exactly
        f32x2 dot = pk_add(pk_add(pk_mul(p.x, qx), pk_mul(p.y, qy)), pk_mul(p.z, qz));
        f32x2 d2  = pk_add(pk_add(p.w, n2), pk_mul(dot, cm2));
        if (d2.x < b0) { b0 = d2.x; i0 = k; }   // strict < keeps first occurrence
        if (d2.y < b1) { b1 = d2.y; i1 = k; }
    }

    part[(size_t)rc * NPTS + j0] = pack_key(b0, rc * RCHUNK + i0);  // coalesced 8B stores
    part[(size_t)rc * NPTS + j1] = pack_key(b1, rc * RCHUNK + i1);
}

// Fused reduce + gather: each block owns GCOLS consecutive output columns.
__global__ __launch_bounds__(256) void gather_kernel(const float* __restrict__ emb1,
                                                     const float* __restrict__ emb2,
                                                     const unsigned long long* __restrict__ part,
                                                     float* __restrict__ out) {
    __shared__ unsigned long long skey[GCOLS][9];   // padded: breaks bank aliasing
    __shared__ int sidx[GCOLS];
    const int tid   = threadIdx.x;
    const int jbase = blockIdx.x * GCOLS;

    // Phase 1: per-column u64-key min over the 64 chunk partials (deterministic).
    {
        int c = tid & 31, g = tid >> 5;            // 8 threads per column
        size_t j = (size_t)(jbase + c);
        unsigned long long m = ~0ULL;
        #pragma unroll
        for (int s8 = 0; s8 < 8; ++s8) {
            unsigned long long k = part[(size_t)(g * 8 + s8) * NPTS + j];  // L2-resident
            m = k < m ? k : m;
        }
        skey[c][g] = m;
    }
    __syncthreads();
    if (tid < GCOLS) {
        unsigned long long m = skey[tid][0];
        #pragma unroll
        for (int g = 1; g < 8; ++g) {
            unsigned long long k = skey[tid][g];
            m = k < m ? k : m;
        }
        sidx[tid] = (int)(m & 8191ULL);            // min d2, tie -> lowest index
    }
    __syncthreads();

    // Phase 2: 512 feature rows x 32 cols; float4 over columns.
    // f is wave-uniform per pass -> uniform branch.
    #pragma unroll
    for (int p = 0; p < 16; ++p) {
        int f  = p * 32 + (tid >> 3);
        int c0 = (tid & 7) * 4;
        float4 v;
        if (f < NFEAT) {
            const float* row = emb1 + (size_t)f * NPTS;   // 32KB row, L1/L2-resident
            v.x = row[sidx[c0 + 0]];
            v.y = row[sidx[c0 + 1]];
            v.z = row[sidx[c0 + 2]];
            v.w = row[sidx[c0 + 3]];
        } else {
            v = *(const float4*)(emb2 + (size_t)(f - NFEAT) * NPTS + jbase + c0);
        }
        *(float4*)(out + (size_t)f * NPTS + jbase + c0) = v;   // coalesced 16B stores
    }
}

extern "C" void kernel_launch(void* const* d_in, const int* in_sizes, int n_in,
                              void* d_out, int out_size, void* d_ws, size_t ws_size,
                              hipStream_t stream) {
    const float* emb1 = (const float*)d_in[0];
    const float* emb2 = (const float*)d_in[1];
    const float* t1   = (const float*)d_in[2];
    const float* t2   = (const float*)d_in[3];
    float* out = (float*)d_out;

    unsigned long long* part = (unsigned long long*)((char*)d_ws + WS_PART_OFF);

    argmin_kernel<<<dim3(NQG, NCHUNK), 256, 0, stream>>>(t1, t2, part);
    gather_kernel<<<dim3(NPTS / GCOLS), 256, 0, stream>>>(emb1, emb2, part, out);
}

// Round 9
// 104.361 us; speedup vs baseline: 1.0213x; 1.0024x over previous
//
#include <hip/hip_runtime.h>

#define NPTS   8192
#define NFEAT  256
#define RCHUNK 128              // refs per chunk
#define NCHUNK (NPTS / RCHUNK)  // 64 chunks
#define QG     512              // queries per block (2 per thread, packed lo/hi)
#define NQG    (NPTS / QG)      // 16  -> argmin grid 16 x 64 = 1024 blocks (4 waves/SIMD)
#define GCOLS  32               // columns per gather block

// ws layout: [0, 4MB) partial keys u64[NCHUNK][NPTS]
#define WS_PART_OFF 0

typedef float f32x2 __attribute__((ext_vector_type(2)));

// VOP3P packed fp32, per-word IEEE RNE; inline asm cannot be FMA-contracted.
// _blo / _bhi broadcast src0's LO / HI 32-bit word to BOTH output halves via op_sel,
// so refs stay un-duplicated in LDS (one ds_read_b128 per ref).
__device__ __forceinline__ f32x2 pk_mul(f32x2 a, f32x2 b) {
    f32x2 d; asm("v_pk_mul_f32 %0, %1, %2" : "=v"(d) : "v"(a), "v"(b)); return d;
}
__device__ __forceinline__ f32x2 pk_add(f32x2 a, f32x2 b) {
    f32x2 d; asm("v_pk_add_f32 %0, %1, %2" : "=v"(d) : "v"(a), "v"(b)); return d;
}
__device__ __forceinline__ f32x2 pk_mul_blo(f32x2 a, f32x2 b) {  // d = {a.lo*b.lo, a.lo*b.hi}
    f32x2 d; asm("v_pk_mul_f32 %0, %1, %2 op_sel:[0,0] op_sel_hi:[0,1]" : "=v"(d) : "v"(a), "v"(b)); return d;
}
__device__ __forceinline__ f32x2 pk_mul_bhi(f32x2 a, f32x2 b) {  // d = {a.hi*b.lo, a.hi*b.hi}
    f32x2 d; asm("v_pk_mul_f32 %0, %1, %2 op_sel:[1,0] op_sel_hi:[1,1]" : "=v"(d) : "v"(a), "v"(b)); return d;
}
__device__ __forceinline__ f32x2 pk_add_bhi(f32x2 a, f32x2 b) {  // d = {a.hi+b.lo, a.hi+b.hi}
    f32x2 d; asm("v_pk_add_f32 %0, %1, %2 op_sel:[1,0] op_sel_hi:[1,1]" : "=v"(d) : "v"(a), "v"(b)); return d;
}

__device__ __forceinline__ unsigned long long pack_key(float d2, int idx) {
    // signed-float -> order-isomorphic u32 (d2 can be negative via cancellation),
    // index in low 13 bits: u64 min == (min d2, tie -> min idx) = np first-occurrence
    unsigned ub = __float_as_uint(d2);
    ub ^= ((unsigned)((int)ub >> 31)) | 0x80000000u;
    return ((unsigned long long)ub << 13) | (unsigned)idx;
}

__global__ __launch_bounds__(256) void argmin_kernel(const float* __restrict__ t1,
                                                     const float* __restrict__ t2,
                                                     unsigned long long* __restrict__ part) {
#pragma clang fp contract(off)   // scalar prologue must also stay RNE, no FMA
    __shared__ float4 sref[RCHUNK];   // {x, y, z, n1} -- no duplication
    const int tid = threadIdx.x;
    const int qg  = blockIdx.x;   // query group 0..15
    const int rc  = blockIdx.y;   // ref chunk   0..63

    // Stage refs into LDS; n1 = (x^2+y^2)+z^2 in np's sequential sum order.
    if (tid < RCHUNK) {
        int r = rc * RCHUNK + tid;
        float x = t1[r], y = t1[NPTS + r], z = t1[2 * NPTS + r];
        sref[tid] = make_float4(x, y, z, (x * x + y * y) + z * z);
    }
    __syncthreads();

    // Two queries per thread, packed into lo/hi words.
    const int j0 = qg * QG + tid;
    const int j1 = j0 + 256;
    float qx0 = t2[j0], qy0 = t2[NPTS + j0], qz0 = t2[2 * NPTS + j0];
    float qx1 = t2[j1], qy1 = t2[NPTS + j1], qz1 = t2[2 * NPTS + j1];
    float n20 = (qx0 * qx0 + qy0 * qy0) + qz0 * qz0;
    float n21 = (qx1 * qx1 + qy1 * qy1) + qz1 * qz1;

    const f32x2 qx = {qx0, qx1}, qy = {qy0, qy1}, qz = {qz0, qz1};
    const f32x2 n2 = {n20, n21};
    const f32x2 cm2 = {-2.0f, -2.0f};

    const float inf = __int_as_float(0x7f800000);
    float b0 = inf, b1 = inf;
    int   i0 = 0,   i1 = 0;

    #pragma unroll 4
    for (int k = 0; k < RCHUNK; ++k) {
        float4 p4 = sref[k];          // wave-uniform addr -> 1x ds_read_b128 broadcast
        f32x2 pxy, pzw;               // alias register pairs (x,y) and (z,n1)
        __builtin_memcpy(&pxy, &p4.x, 8);
        __builtin_memcpy(&pzw, &p4.z, 8);
        // np expanded form, exact op order per query half:
        //   dot = (x1*x2 + y1*y2) + z1*z2
        //   d2  = (n1 + n2) + (dot * -2)     == (n1+n2) - 2*dot bit-exactly
        f32x2 s1  = pk_add(pk_mul_blo(pxy, qx), pk_mul_bhi(pxy, qy));
        f32x2 dot = pk_add(s1, pk_mul_blo(pzw, qz));
        f32x2 nn  = pk_add_bhi(pzw, n2);
        f32x2 d2  = pk_add(nn, pk_mul(dot, cm2));
        if (d2.x < b0) { b0 = d2.x; i0 = k; }   // strict < keeps first occurrence
        if (d2.y < b1) { b1 = d2.y; i1 = k; }
    }

    part[(size_t)rc * NPTS + j0] = pack_key(b0, rc * RCHUNK + i0);  // coalesced 8B stores
    part[(size_t)rc * NPTS + j1] = pack_key(b1, rc * RCHUNK + i1);
}

// Fused reduce + gather: each block owns GCOLS consecutive output columns.
__global__ __launch_bounds__(256) void gather_kernel(const float* __restrict__ emb1,
                                                     const float* __restrict__ emb2,
                                                     const unsigned long long* __restrict__ part,
                                                     float* __restrict__ out) {
    __shared__ unsigned long long skey[GCOLS][9];   // padded: breaks bank aliasing
    __shared__ int sidx[GCOLS];
    const int tid   = threadIdx.x;
    const int jbase = blockIdx.x * GCOLS;

    // Phase 1: per-column u64-key min over the 64 chunk partials (deterministic).
    {
        int c = tid & 31, g = tid >> 5;            // 8 threads per column
        size_t j = (size_t)(jbase + c);
        unsigned long long m = ~0ULL;
        #pragma unroll
        for (int s8 = 0; s8 < 8; ++s8) {
            unsigned long long k = part[(size_t)(g * 8 + s8) * NPTS + j];  // L2-resident
            m = k < m ? k : m;
        }
        skey[c][g] = m;
    }
    __syncthreads();
    if (tid < GCOLS) {
        unsigned long long m = skey[tid][0];
        #pragma unroll
        for (int g = 1; g < 8; ++g) {
            unsigned long long k = skey[tid][g];
            m = k < m ? k : m;
        }
        sidx[tid] = (int)(m & 8191ULL);            // min d2, tie -> lowest index
    }
    __syncthreads();

    // Phase 2: 512 feature rows x 32 cols; float4 over columns.
    // f is wave-uniform per pass -> uniform branch.
    #pragma unroll
    for (int p = 0; p < 16; ++p) {
        int f  = p * 32 + (tid >> 3);
        int c0 = (tid & 7) * 4;
        float4 v;
        if (f < NFEAT) {
            const float* row = emb1 + (size_t)f * NPTS;   // 32KB row, L1/L2-resident
            v.x = row[sidx[c0 + 0]];
            v.y = row[sidx[c0 + 1]];
            v.z = row[sidx[c0 + 2]];
            v.w = row[sidx[c0 + 3]];
        } else {
            v = *(const float4*)(emb2 + (size_t)(f - NFEAT) * NPTS + jbase + c0);
        }
        *(float4*)(out + (size_t)f * NPTS + jbase + c0) = v;   // coalesced 16B stores
    }
}

extern "C" void kernel_launch(void* const* d_in, const int* in_sizes, int n_in,
                              void* d_out, int out_size, void* d_ws, size_t ws_size,
                              hipStream_t stream) {
    const float* emb1 = (const float*)d_in[0];
    const float* emb2 = (const float*)d_in[1];
    const float* t1   = (const float*)d_in[2];
    const float* t2   = (const float*)d_in[3];
    float* out = (float*)d_out;

    unsigned long long* part = (unsigned long long*)((char*)d_ws + WS_PART_OFF);

    argmin_kernel<<<dim3(NQG, NCHUNK), 256, 0, stream>>>(t1, t2, part);
    gather_kernel<<<dim3(NPTS / GCOLS), 256, 0, stream>>>(emb1, emb2, part, out);
}